// Round 1
// baseline (564.764 us; speedup 1.0000x reference)
//
#include <hip/hip_runtime.h>
#include <stdint.h>

typedef unsigned int u32;
typedef __bf16   bf16_t;
typedef _Float16 f16_t;

typedef __bf16   bf16x8 __attribute__((ext_vector_type(8)));
typedef _Float16 f16x8  __attribute__((ext_vector_type(8)));
typedef float    f32x4  __attribute__((ext_vector_type(4)));

template<typename T> struct VecT;
template<> struct VecT<bf16_t> { typedef bf16x8 v8; };
template<> struct VecT<f16_t>  { typedef f16x8  v8; };

__device__ __forceinline__ f32x4 mfma_16x16x32(bf16x8 a, bf16x8 b, f32x4 c){
  return __builtin_amdgcn_mfma_f32_16x16x32_bf16(a, b, c, 0, 0, 0);
}
__device__ __forceinline__ f32x4 mfma_16x16x32(f16x8 a, f16x8 b, f32x4 c){
  return __builtin_amdgcn_mfma_f32_16x16x32_f16(a, b, c, 0, 0, 0);
}

// async global->LDS, 16B per lane; LDS dest is wave-uniform base + lane*16
__device__ __forceinline__ void gl_lds16(const void* g, void* l){
  typedef const __attribute__((address_space(1))) void* gasp;
  typedef __attribute__((address_space(3))) void* lasp;
  gasp gp = reinterpret_cast<gasp>(reinterpret_cast<uintptr_t>(g));
  lasp lp = reinterpret_cast<lasp>(static_cast<u32>(reinterpret_cast<uintptr_t>(l)));
  __builtin_amdgcn_global_load_lds(gp, lp, 16, 0, 0);
}

// Stage a [NROWS][ROWB bytes] tile: LDS[row][c'] = G[row][c' ^ sw(row)], sw = (row&7)<<4.
// Linear LDS dest (gl_lds requirement), pre-swizzled global source.
template<int NBYTES, int ROWB, int NT>
__device__ __forceinline__ void stage_swz(const char* gbase, u32 gstrideB, char* lds, int tid){
  const u32 lane = (u32)(tid & 63);
  #pragma unroll
  for (int j = 0; j < NBYTES/(NT*16); ++j){
    u32 o   = (u32)(j*NT + tid) * 16u;
    u32 row = o / (u32)ROWB;
    u32 col = (o % (u32)ROWB) ^ ((row & 7u) << 4);
    gl_lds16(gbase + (size_t)row * gstrideB + col, lds + (o - lane*16u));
  }
}

template<typename V8>
__device__ __forceinline__ V8 frag_ld(const char* lds, u32 row, u32 rowB, u32 kbyte){
  return *reinterpret_cast<const V8*>(lds + (size_t)row*rowB + (kbyte ^ ((row & 7u) << 4)));
}

// ---------------- converts ----------------
template<typename T>
__global__ void cvt_f32(const float* __restrict__ in, T* __restrict__ out, u32 n8){
  u32 i = blockIdx.x*256u + threadIdx.x;
  if (i >= n8) return;
  const f32x4* p = reinterpret_cast<const f32x4*>(in) + 2*(size_t)i;
  f32x4 a = p[0], b = p[1];
  typename VecT<T>::v8 v;
  v[0]=(T)a[0]; v[1]=(T)a[1]; v[2]=(T)a[2]; v[3]=(T)a[3];
  v[4]=(T)b[0]; v[5]=(T)b[1]; v[6]=(T)b[2]; v[7]=(T)b[3];
  *(reinterpret_cast<typename VecT<T>::v8*>(out) + i) = v;
}

template<typename T>
__global__ void transpose_cvt(const float* __restrict__ W, T* __restrict__ WT, u32 K, u32 N){
  __shared__ float tile[32][33];
  const u32 k0 = blockIdx.x*32u, n0 = blockIdx.y*32u;
  const int t = threadIdx.x;
  const int r = t >> 3, c4 = (t & 7) * 4;
  f32x4 v = *reinterpret_cast<const f32x4*>(W + (size_t)(k0 + r)*N + n0 + c4);
  tile[r][c4+0]=v[0]; tile[r][c4+1]=v[1]; tile[r][c4+2]=v[2]; tile[r][c4+3]=v[3];
  __syncthreads();
  union { T x[4]; uint64_t u; } pk;
  #pragma unroll
  for (int j=0;j<4;++j) pk.x[j] = (T)tile[c4+j][r];
  *reinterpret_cast<uint64_t*>(WT + (size_t)(n0 + r)*K + k0 + c4) = pk.u;
}

__global__ void maskbias_k(const int* __restrict__ mask, const int* __restrict__ rmask,
                           float* __restrict__ mb, float* __restrict__ rb){
  u32 i = blockIdx.x*256u + threadIdx.x;
  if (i < 8192u){
    int m = mask[i]; int r = rmask[i];
    mb[i] = m ? 0.0f : -1.25e9f;           // NEG/8 (mask applied before /scale in ref)
    rb[i] = (m && r) ? 0.0f : -1e10f;      // NEG
  }
}

// ---------------- GEMM: C = A * B^T (+bias) ----------------
// A: [M][lda] T row-major; Bt: [N][ldb] T row-major. Tile 128x128, BK=64, 4 waves (2x2), wave 64x64.
// MODE 0: f32 out, C[m*ldc+n]. MODE 1: T out "head": ((b*16+h)*1024+s)*64+d.
// MODE 2: T out "VT": ((m>>10)*ldc + n)*1024 + (m&1023)  (ldc = N). MODE 3: T out plain: m*ldc+n.
template<typename T, int MODE>
__global__ __launch_bounds__(256, 2)
void gemm_bt(const T* __restrict__ A, u32 lda,
             const T* __restrict__ Bt, u32 ldb,
             const float* __restrict__ bias,
             void* __restrict__ Cout, u32 ldc, u32 K)
{
  __shared__ char As[2][16384];
  __shared__ char Bs[2][16384];
  typedef typename VecT<T>::v8 V8;
  const int tid = threadIdx.x, lane = tid & 63, wid = tid >> 6;
  const int wr = wid >> 1, wc = wid & 1;
  const u32 bn = blockIdx.x * 128u, bm = blockIdx.y * 128u;
  const char* Ab = (const char*)(A + (size_t)bm * lda);
  const char* Bb = (const char*)(Bt + (size_t)bn * ldb);
  const u32 ldaB = lda*2u, ldbB = ldb*2u;

  f32x4 acc[4][4] = {};
  const int nt = (int)(K >> 6);

  stage_swz<16384,128,256>(Ab, ldaB, As[0], tid);
  stage_swz<16384,128,256>(Bb, ldbB, Bs[0], tid);
  __syncthreads();

  for (int t = 0; t < nt; ++t){
    if (t + 1 < nt){
      stage_swz<16384,128,256>(Ab + (size_t)(t+1)*128, ldaB, As[(t+1)&1], tid);
      stage_swz<16384,128,256>(Bb + (size_t)(t+1)*128, ldbB, Bs[(t+1)&1], tid);
    }
    const char* as = As[t&1]; const char* bs = Bs[t&1];
    V8 af[4][2], bf[4][2];
    #pragma unroll
    for (int mi=0; mi<4; ++mi)
      #pragma unroll
      for (int ks=0; ks<2; ++ks)
        af[mi][ks] = frag_ld<V8>(as, (u32)(wr*64 + mi*16 + (lane&15)), 128u, (u32)(ks*64 + ((lane>>4)<<4)));
    #pragma unroll
    for (int ni=0; ni<4; ++ni)
      #pragma unroll
      for (int ks=0; ks<2; ++ks)
        bf[ni][ks] = frag_ld<V8>(bs, (u32)(wc*64 + ni*16 + (lane&15)), 128u, (u32)(ks*64 + ((lane>>4)<<4)));
    #pragma unroll
    for (int mi=0; mi<4; ++mi)
      #pragma unroll
      for (int ni=0; ni<4; ++ni)
        #pragma unroll
        for (int ks=0; ks<2; ++ks)
          acc[mi][ni] = mfma_16x16x32(af[mi][ks], bf[ni][ks], acc[mi][ni]);
    __syncthreads();
  }

  float bv[4];
  #pragma unroll
  for (int ni=0; ni<4; ++ni) bv[ni] = bias[bn + wc*64 + ni*16 + (lane&15)];

  #pragma unroll
  for (int mi=0; mi<4; ++mi){
    #pragma unroll
    for (int ni=0; ni<4; ++ni){
      u32 n  = bn + (u32)(wc*64 + ni*16 + (lane&15));
      u32 m0 = bm + (u32)(wr*64 + mi*16 + ((lane>>4)<<2));
      if constexpr (MODE == 0){
        float* C = (float*)Cout;
        #pragma unroll
        for (int r=0;r<4;++r) C[(size_t)(m0+r)*ldc + n] = acc[mi][ni][r] + bv[ni];
      } else if constexpr (MODE == 1){
        T* C = (T*)Cout;
        #pragma unroll
        for (int r=0;r<4;++r){
          u32 m = m0 + r;
          size_t idx = (((size_t)(m>>10)*16 + (n>>6))*1024 + (m&1023))*64 + (n&63);
          C[idx] = (T)(acc[mi][ni][r] + bv[ni]);
        }
      } else if constexpr (MODE == 2){
        T* C = (T*)Cout;
        size_t idx0 = ((size_t)(m0>>10)*ldc + n)*1024 + (m0 & 1023);
        union { T v[4]; uint64_t u; } pk;
        #pragma unroll
        for (int r=0;r<4;++r) pk.v[r] = (T)(acc[mi][ni][r] + bv[ni]);
        *reinterpret_cast<uint64_t*>(C + idx0) = pk.u;
      } else {
        T* C = (T*)Cout;
        #pragma unroll
        for (int r=0;r<4;++r) C[(size_t)(m0+r)*ldc + n] = (T)(acc[mi][ni][r] + bv[ni]);
      }
    }
  }
}

// ---------------- attention pass 1: online row max / sumexp ----------------
// S^T form: block = 128 q-cols x S k-rows, chunk of 64 k. 8 waves: wr=k-half(32), wc=q-quarter(32).
template<typename T, int D, int BSHIFT, int SCALEBIT>
__global__ __launch_bounds__(512)
void attn_pass1(const T* __restrict__ Qg, const T* __restrict__ Kg,
                const float* __restrict__ mbias,
                float* __restrict__ statM, float* __restrict__ statR)
{
  constexpr int S = 1024, KCH = 64;
  constexpr u32 ROWB = D*2;
  typedef typename VecT<T>::v8 V8;
  __shared__ char Qs[128*D*2];
  __shared__ char Ks[2][KCH*D*2];
  __shared__ float mrow[128], lrow[128];
  __shared__ float wmax[2][128], wsum[2][128];

  const int tid = threadIdx.x, lane = tid & 63, wid = tid >> 6;
  const int wr = wid >> 2, wc = wid & 3;
  const u32 qt = blockIdx.x, batch = blockIdx.y;
  const float scale = SCALEBIT ? 0.125f : 1.0f;
  const T* qb = Qg + ((size_t)batch*S + (size_t)qt*128)*D;
  const T* kb = Kg + (size_t)batch*S*D;
  const float* mbb = mbias + (size_t)(batch >> BSHIFT)*S;

  stage_swz<128*D*2, (int)ROWB, 512>((const char*)qb, ROWB, Qs, tid);
  stage_swz<KCH*D*2, (int)ROWB, 512>((const char*)kb, ROWB, Ks[0], tid);
  if (tid < 128){ mrow[tid] = -1e30f; lrow[tid] = 0.0f; }
  __syncthreads();

  constexpr int NCH = S / KCH;
  for (int ch = 0; ch < NCH; ++ch){
    if (ch + 1 < NCH)
      stage_swz<KCH*D*2, (int)ROWB, 512>((const char*)(kb + (size_t)(ch+1)*KCH*D), ROWB, Ks[(ch+1)&1], tid);
    const char* ks = Ks[ch&1];

    f32x4 mb[2];
    #pragma unroll
    for (int mi=0; mi<2; ++mi)
      mb[mi] = *reinterpret_cast<const f32x4*>(mbb + ch*KCH + wr*32 + mi*16 + ((lane>>4)<<2));

    f32x4 acc[2][2] = {};
    #pragma unroll
    for (int ksl=0; ksl<D/32; ++ksl){
      V8 af[2], bf[2];
      #pragma unroll
      for (int mi=0; mi<2; ++mi)
        af[mi] = frag_ld<V8>(ks, (u32)(wr*32 + mi*16 + (lane&15)), ROWB, (u32)(ksl*64 + ((lane>>4)<<4)));
      #pragma unroll
      for (int ni=0; ni<2; ++ni)
        bf[ni] = frag_ld<V8>(Qs, (u32)(wc*32 + ni*16 + (lane&15)), ROWB, (u32)(ksl*64 + ((lane>>4)<<4)));
      #pragma unroll
      for (int mi=0; mi<2; ++mi)
        #pragma unroll
        for (int ni=0; ni<2; ++ni)
          acc[mi][ni] = mfma_16x16x32(af[mi], bf[ni], acc[mi][ni]);
    }

    float e[2][2][4];
    #pragma unroll
    for (int mi=0; mi<2; ++mi)
      #pragma unroll
      for (int ni=0; ni<2; ++ni)
        #pragma unroll
        for (int r=0;r<4;++r)
          e[mi][ni][r] = acc[mi][ni][r]*scale + mb[mi][r];

    float cm[2];
    #pragma unroll
    for (int ni=0; ni<2; ++ni){
      float v = -3.0e38f;
      #pragma unroll
      for (int mi=0; mi<2; ++mi)
        #pragma unroll
        for (int r=0;r<4;++r) v = fmaxf(v, e[mi][ni][r]);
      v = fmaxf(v, __shfl_xor(v, 16));
      v = fmaxf(v, __shfl_xor(v, 32));
      cm[ni] = v;
    }
    if ((lane >> 4) == 0){
      #pragma unroll
      for (int ni=0; ni<2; ++ni) wmax[wr][wc*32 + ni*16 + lane] = cm[ni];
    }
    __syncthreads();

    float mn[2];
    #pragma unroll
    for (int ni=0; ni<2; ++ni){
      u32 q = (u32)(wc*32 + ni*16 + (lane&15));
      mn[ni] = fmaxf(mrow[q], fmaxf(wmax[0][q], wmax[1][q]));
    }
    float sv[2];
    #pragma unroll
    for (int ni=0; ni<2; ++ni){
      float s = 0.0f;
      #pragma unroll
      for (int mi=0; mi<2; ++mi)
        #pragma unroll
        for (int r=0;r<4;++r) s += expf(e[mi][ni][r] - mn[ni]);
      s += __shfl_xor(s, 16);
      s += __shfl_xor(s, 32);
      sv[ni] = s;
    }
    if ((lane >> 4) == 0){
      #pragma unroll
      for (int ni=0; ni<2; ++ni) wsum[wr][wc*32 + ni*16 + lane] = sv[ni];
    }
    __syncthreads();

    if (tid < 128){
      float mo = mrow[tid];
      float mnn = fmaxf(mo, fmaxf(wmax[0][tid], wmax[1][tid]));
      lrow[tid] = lrow[tid]*expf(mo - mnn) + wsum[0][tid] + wsum[1][tid];
      mrow[tid] = mnn;
    }
    __syncthreads();
  }

  if (tid < 128){
    size_t idx = (size_t)batch*S + (size_t)qt*128 + tid;
    statM[idx] = mrow[tid];
    statR[idx] = 1.0f / lrow[tid];
  }
}

// ---------------- attention pass 2: softmax write + fused PV ----------------
template<typename T, typename TO, int D, int BSHIFT, int SCALEBIT>
__global__ __launch_bounds__(512)
void attn_pass2(const T* __restrict__ Qg, const T* __restrict__ Kg, const T* __restrict__ Vtg,
                const float* __restrict__ mbias,
                const float* __restrict__ statM, const float* __restrict__ statR,
                float* __restrict__ attnOut,
                TO* __restrict__ xout, u32 xld, u32 xcolAdd)
{
  constexpr int S = 1024, KCH = 64;
  constexpr u32 ROWB = D*2;
  constexpr int MIPV = D/32;
  typedef typename VecT<T>::v8 V8;
  __shared__ char Qs[128*D*2];
  __shared__ char Ks[2][KCH*D*2];
  __shared__ char Vs[2][D*KCH*2];
  __shared__ float Pout[128*KCH];

  const int tid = threadIdx.x, lane = tid & 63, wid = tid >> 6;
  const int wr = wid >> 2, wc = wid & 3;
  const u32 qt = blockIdx.x, batch = blockIdx.y;
  const u32 bb = batch >> BSHIFT;
  const float scale = SCALEBIT ? 0.125f : 1.0f;
  const T* qb = Qg + ((size_t)batch*S + (size_t)qt*128)*D;
  const T* kb = Kg + (size_t)batch*S*D;
  const char* vtb = (const char*)(Vtg + (size_t)batch*D*S);
  const float* mbb = mbias + (size_t)bb*S;
  char* poutb = (char*)Pout;

  float mreg[2], rreg[2];
  #pragma unroll
  for (int ni=0; ni<2; ++ni){
    u32 q = qt*128u + (u32)(wc*32 + ni*16 + (lane&15));
    mreg[ni] = statM[(size_t)batch*S + q];
    rreg[ni] = statR[(size_t)batch*S + q];
  }
  f32x4 accX[MIPV][2] = {};

  stage_swz<128*D*2, (int)ROWB, 512>((const char*)qb, ROWB, Qs, tid);
  stage_swz<KCH*D*2, (int)ROWB, 512>((const char*)kb, ROWB, Ks[0], tid);
  stage_swz<D*KCH*2, 128, 512>(vtb, (u32)(S*2), Vs[0], tid);
  __syncthreads();

  constexpr int NCH = S / KCH;
  for (int ch = 0; ch < NCH; ++ch){
    if (ch + 1 < NCH){
      stage_swz<KCH*D*2, (int)ROWB, 512>((const char*)(kb + (size_t)(ch+1)*KCH*D), ROWB, Ks[(ch+1)&1], tid);
      stage_swz<D*KCH*2, 128, 512>(vtb + (size_t)(ch+1)*KCH*2, (u32)(S*2), Vs[(ch+1)&1], tid);
    }
    const char* ks = Ks[ch&1];
    const char* vs = Vs[ch&1];

    f32x4 mb[2];
    #pragma unroll
    for (int mi=0; mi<2; ++mi)
      mb[mi] = *reinterpret_cast<const f32x4*>(mbb + ch*KCH + wr*32 + mi*16 + ((lane>>4)<<2));

    f32x4 acc[2][2] = {};
    #pragma unroll
    for (int ksl=0; ksl<D/32; ++ksl){
      V8 af[2], bf[2];
      #pragma unroll
      for (int mi=0; mi<2; ++mi)
        af[mi] = frag_ld<V8>(ks, (u32)(wr*32 + mi*16 + (lane&15)), ROWB, (u32)(ksl*64 + ((lane>>4)<<4)));
      #pragma unroll
      for (int ni=0; ni<2; ++ni)
        bf[ni] = frag_ld<V8>(Qs, (u32)(wc*32 + ni*16 + (lane&15)), ROWB, (u32)(ksl*64 + ((lane>>4)<<4)));
      #pragma unroll
      for (int mi=0; mi<2; ++mi)
        #pragma unroll
        for (int ni=0; ni<2; ++ni)
          acc[mi][ni] = mfma_16x16x32(af[mi], bf[ni], acc[mi][ni]);
    }

    // p = exp(e - m)/l  ->  Pout[q][k] (swizzled)
    #pragma unroll
    for (int ni=0; ni<2; ++ni){
      u32 q = (u32)(wc*32 + ni*16 + (lane&15));
      #pragma unroll
      for (int mi=0; mi<2; ++mi){
        f32x4 pv;
        #pragma unroll
        for (int r=0;r<4;++r){
          float e = acc[mi][ni][r]*scale + mb[mi][r];
          pv[r] = expf(e - mreg[ni]) * rreg[ni];
        }
        u32 k0b = (u32)(wr*32 + mi*16 + ((lane>>4)<<2)) * 4u;
        *reinterpret_cast<f32x4*>(poutb + (size_t)q*256 + (k0b ^ ((q&7u)<<4))) = pv;
      }
    }
    __syncthreads();

    // PV: x^T[d][q] += Vt[d][s] * P^T[s][q]
    #pragma unroll
    for (int ksl=0; ksl<2; ++ksl){
      V8 pb[2];
      #pragma unroll
      for (int ni=0; ni<2; ++ni){
        u32 q = (u32)(wc*32 + ni*16 + (lane&15));
        u32 kb0 = (u32)(ksl*128 + ((lane>>4)<<5));
        f32x4 p0 = *reinterpret_cast<const f32x4*>(poutb + (size_t)q*256 + ((kb0      ) ^ ((q&7u)<<4)));
        f32x4 p1 = *reinterpret_cast<const f32x4*>(poutb + (size_t)q*256 + ((kb0 + 16u) ^ ((q&7u)<<4)));
        V8 v;
        v[0]=(T)p0[0]; v[1]=(T)p0[1]; v[2]=(T)p0[2]; v[3]=(T)p0[3];
        v[4]=(T)p1[0]; v[5]=(T)p1[1]; v[6]=(T)p1[2]; v[7]=(T)p1[3];
        pb[ni] = v;
      }
      #pragma unroll
      for (int mi=0; mi<MIPV; ++mi){
        V8 vf = frag_ld<V8>(vs, (u32)(wr*(D/2) + mi*16 + (lane&15)), 128u, (u32)(ksl*64 + ((lane>>4)<<4)));
        #pragma unroll
        for (int ni=0; ni<2; ++ni)
          accX[mi][ni] = mfma_16x16x32(vf, pb[ni], accX[mi][ni]);
      }
    }

    // coalesced attention store
    {
      u32 q2 = (u32)tid >> 2;
      float* abase = attnOut + (size_t)batch*S*S + ((size_t)qt*128 + q2)*S + (size_t)ch*KCH;
      #pragma unroll
      for (int j=0;j<4;++j){
        u32 kbyte = ((u32)(tid&3) + 4u*(u32)j)*16u;
        f32x4 v = *reinterpret_cast<const f32x4*>(poutb + (size_t)q2*256 + (kbyte ^ ((q2&7u)<<4)));
        *reinterpret_cast<f32x4*>(abase + (kbyte>>2)) = v;
      }
    }
    __syncthreads();
  }

  // write x^T to concat buffer
  u32 col0 = (batch & ((1u<<BSHIFT)-1u)) * (u32)D + xcolAdd;
  #pragma unroll
  for (int mi=0; mi<MIPV; ++mi){
    #pragma unroll
    for (int ni=0; ni<2; ++ni){
      u32 d = (u32)(wr*(D/2) + mi*16 + ((lane>>4)<<2));
      u32 q = qt*128u + (u32)(wc*32 + ni*16 + (lane&15));
      union { TO v[4]; uint64_t u; } pk;
      #pragma unroll
      for (int r=0;r<4;++r) pk.v[r] = (TO)accX[mi][ni][r];
      *reinterpret_cast<uint64_t*>(xout + ((size_t)bb*S + q)*xld + col0 + d) = pk.u;
    }
  }
}

// ---------------- launch ----------------
extern "C" void kernel_launch(void* const* d_in, const int* in_sizes, int n_in,
                              void* d_out, int out_size, void* d_ws, size_t ws_size,
                              hipStream_t stream)
{
  const float* query = (const float*)d_in[0];
  const float* key   = (const float*)d_in[1];
  const float* value = (const float*)d_in[2];
  const float* x_rsa = (const float*)d_in[3];
  const int*   mask  = (const int*)d_in[4];
  const int*   rmask = (const int*)d_in[5];
  const float* Wq = (const float*)d_in[6];  const float* bq = (const float*)d_in[7];
  const float* Wk = (const float*)d_in[8];  const float* bk = (const float*)d_in[9];
  const float* Wv = (const float*)d_in[10]; const float* bv = (const float*)d_in[11];
  const float* Wsk= (const float*)d_in[12]; const float* bsk= (const float*)d_in[13];
  const float* Wsv= (const float*)d_in[14]; const float* bsv= (const float*)d_in[15];
  const float* Wo = (const float*)d_in[16]; const float* bo = (const float*)d_in[17];

  char* ws = (char*)d_ws;
  size_t off = 0;
  auto alloc = [&](size_t bytes)->char*{ char* p = ws + off; off += (bytes + 255) & ~(size_t)255; return p; };

  bf16_t* q16  = (bf16_t*)alloc(16777216);
  bf16_t* k16  = (bf16_t*)alloc(16777216);
  bf16_t* v16  = (bf16_t*)alloc(16777216);
  f16_t*  kf   = (f16_t*) alloc(16777216);
  f16_t*  vf   = (f16_t*) alloc(16777216);
  f16_t*  xrf  = (f16_t*) alloc(2097152);
  bf16_t* wqT  = (bf16_t*)alloc(2097152);
  bf16_t* wkT  = (bf16_t*)alloc(2097152);
  bf16_t* wvT  = (bf16_t*)alloc(2097152);
  f16_t*  wskT = (f16_t*) alloc(262144);
  f16_t*  wsvT = (f16_t*) alloc(262144);
  bf16_t* woT  = (bf16_t*)alloc(2359296);
  bf16_t* Qh   = (bf16_t*)alloc(16777216);
  bf16_t* Kh   = (bf16_t*)alloc(16777216);
  bf16_t* Vth  = (bf16_t*)alloc(16777216);
  f16_t*  strK = (f16_t*) alloc(2097152);
  f16_t*  strVt= (f16_t*) alloc(2097152);
  bf16_t* conc = (bf16_t*)alloc(18874368);
  float*  stMm = (float*) alloc(524288);
  float*  stRm = (float*) alloc(524288);
  float*  stMr = (float*) alloc(32768);
  float*  stRr = (float*) alloc(32768);
  float*  mbias= (float*) alloc(32768);
  float*  rbias= (float*) alloc(32768);

  // converts
  cvt_f32<bf16_t><<<4096,256,0,stream>>>(query, q16, 1048576);
  cvt_f32<bf16_t><<<4096,256,0,stream>>>(key,   k16, 1048576);
  cvt_f32<bf16_t><<<4096,256,0,stream>>>(value, v16, 1048576);
  cvt_f32<f16_t> <<<4096,256,0,stream>>>(key,   kf,  1048576);
  cvt_f32<f16_t> <<<4096,256,0,stream>>>(value, vf,  1048576);
  cvt_f32<f16_t> <<<512, 256,0,stream>>>(x_rsa, xrf, 131072);
  transpose_cvt<bf16_t><<<dim3(32,32),256,0,stream>>>(Wq,  wqT,  1024, 1024);
  transpose_cvt<bf16_t><<<dim3(32,32),256,0,stream>>>(Wk,  wkT,  1024, 1024);
  transpose_cvt<bf16_t><<<dim3(32,32),256,0,stream>>>(Wv,  wvT,  1024, 1024);
  transpose_cvt<f16_t> <<<dim3(32,4), 256,0,stream>>>(Wsk, wskT, 1024, 128);
  transpose_cvt<f16_t> <<<dim3(32,4), 256,0,stream>>>(Wsv, wsvT, 1024, 128);
  transpose_cvt<bf16_t><<<dim3(36,32),256,0,stream>>>(Wo,  woT,  1152, 1024);
  maskbias_k<<<32,256,0,stream>>>(mask, rmask, mbias, rbias);

  // projections
  gemm_bt<bf16_t,1><<<dim3(8,64),256,0,stream>>>(q16,1024, wqT,1024, bq, (void*)Qh,  0,    1024);
  gemm_bt<bf16_t,1><<<dim3(8,64),256,0,stream>>>(k16,1024, wkT,1024, bk, (void*)Kh,  0,    1024);
  gemm_bt<bf16_t,2><<<dim3(8,64),256,0,stream>>>(v16,1024, wvT,1024, bv, (void*)Vth, 1024, 1024);
  gemm_bt<f16_t, 3><<<dim3(1,64),256,0,stream>>>(kf, 1024, wskT,1024, bsk,(void*)strK, 128, 1024);
  gemm_bt<f16_t, 2><<<dim3(1,64),256,0,stream>>>(vf, 1024, wsvT,1024, bsv,(void*)strVt,128, 1024);

  // attention stats
  attn_pass1<bf16_t,64,4,1><<<dim3(8,128),512,0,stream>>>(Qh, Kh, mbias, stMm, stRm);
  attn_pass1<f16_t,128,0,0><<<dim3(8,8),  512,0,stream>>>(xrf, strK, rbias, stMr, stRr);

  float* outp  = (float*)d_out;
  float* attnp = outp + 8388608;
  float* rsap  = outp + 8388608 + 134217728;

  // attention pass2 (softmax out + PV into concat)
  attn_pass2<bf16_t,bf16_t,64,4,1><<<dim3(8,128),512,0,stream>>>(Qh, Kh, Vth, mbias, stMm, stRm, attnp, conc, 1152, 0);
  attn_pass2<f16_t, bf16_t,128,0,0><<<dim3(8,8), 512,0,stream>>>(xrf, strK, strVt, rbias, stMr, stRr, rsap, conc, 1152, 1024);

  // output projection
  gemm_bt<bf16_t,0><<<dim3(8,64),256,0,stream>>>(conc,1152, woT,1152, bo, (void*)outp, 1024, 1152);

  (void)in_sizes; (void)n_in; (void)out_size; (void)ws_size;
}

// Round 2
// 428.714 us; speedup vs baseline: 1.3173x; 1.3173x over previous
//
#include <hip/hip_runtime.h>
#include <stdint.h>

typedef unsigned int u32;
typedef _Float16 f16_t;

typedef _Float16 f16x8 __attribute__((ext_vector_type(8)));
typedef float    f32x4 __attribute__((ext_vector_type(4)));

__device__ __forceinline__ f32x4 mfma16(f16x8 a, f16x8 b, f32x4 c){
  return __builtin_amdgcn_mfma_f32_16x16x32_f16(a, b, c, 0, 0, 0);
}
__device__ __forceinline__ float fexp2(float x){ return __builtin_amdgcn_exp2f(x); }

// async global->LDS, 16B per lane; LDS dest is wave-uniform base + lane*16
__device__ __forceinline__ void gl_lds16(const void* g, void* l){
  typedef const __attribute__((address_space(1))) void* gasp;
  typedef __attribute__((address_space(3))) void* lasp;
  gasp gp = reinterpret_cast<gasp>(reinterpret_cast<uintptr_t>(g));
  lasp lp = reinterpret_cast<lasp>(static_cast<u32>(reinterpret_cast<uintptr_t>(l)));
  __builtin_amdgcn_global_load_lds(gp, lp, 16, 0, 0);
}

// Stage a [NROWS][ROWB bytes] tile: LDS[row][c'] = G[row][c' ^ sw(row)], sw = (row&7)<<4.
template<int NBYTES, int ROWB, int NT>
__device__ __forceinline__ void stage_swz(const char* gbase, u32 gstrideB, char* lds, int tid){
  const u32 lane = (u32)(tid & 63);
  #pragma unroll
  for (int j = 0; j < NBYTES/(NT*16); ++j){
    u32 o   = (u32)(j*NT + tid) * 16u;
    u32 row = o / (u32)ROWB;
    u32 col = (o % (u32)ROWB) ^ ((row & 7u) << 4);
    gl_lds16(gbase + (size_t)row * gstrideB + col, lds + (o - lane*16u));
  }
}

__device__ __forceinline__ f16x8 frag_ld(const char* lds, u32 row, u32 rowB, u32 kbyte){
  return *reinterpret_cast<const f16x8*>(lds + (size_t)row*rowB + (kbyte ^ ((row & 7u) << 4)));
}

// ---------------- prep: converts + mask bias, one launch ----------------
__device__ __forceinline__ void cvt8(const float* __restrict__ in, f16_t* __restrict__ out, u32 i){
  const f32x4* p = reinterpret_cast<const f32x4*>(in) + 2*(size_t)i;
  f32x4 a = p[0], b = p[1];
  f16x8 v;
  v[0]=(f16_t)a[0]; v[1]=(f16_t)a[1]; v[2]=(f16_t)a[2]; v[3]=(f16_t)a[3];
  v[4]=(f16_t)b[0]; v[5]=(f16_t)b[1]; v[6]=(f16_t)b[2]; v[7]=(f16_t)b[3];
  *(reinterpret_cast<f16x8*>(out) + i) = v;
}

__global__ void prep_all(const float* __restrict__ q, const float* __restrict__ k,
                         const float* __restrict__ v, const float* __restrict__ xr,
                         const int* __restrict__ mask, const int* __restrict__ rmask,
                         f16_t* __restrict__ qo, f16_t* __restrict__ ko,
                         f16_t* __restrict__ vo, f16_t* __restrict__ xo,
                         float* __restrict__ mb, float* __restrict__ rb){
  u32 b = blockIdx.x;
  if (b < 12288u){
    const float* in; f16_t* out; u32 base;
    if (b < 4096u){ in=q; out=qo; base=0u; }
    else if (b < 8192u){ in=k; out=ko; base=4096u; }
    else { in=v; out=vo; base=8192u; }
    cvt8(in, out, (b-base)*256u + threadIdx.x);
  } else if (b < 12800u){
    cvt8(xr, xo, (b-12288u)*256u + threadIdx.x);
  } else {
    u32 i = (b-12800u)*256u + threadIdx.x;
    int m = mask[i]; int r = rmask[i];
    mb[i] = m ? 0.0f : -1.0e9f;          // log2-domain bias: exp2(-1e9)=0
    rb[i] = (m && r) ? 0.0f : -1.0e9f;
  }
}

// ---------------- weight transpose+convert (z-batched) ----------------
__global__ void transpose_cvt(const float* __restrict__ W0, const float* __restrict__ W1,
                              const float* __restrict__ W2,
                              f16_t* __restrict__ T0, f16_t* __restrict__ T1, f16_t* __restrict__ T2,
                              u32 K, u32 N){
  const float* W = blockIdx.z==0 ? W0 : blockIdx.z==1 ? W1 : W2;
  f16_t* WT      = blockIdx.z==0 ? T0 : blockIdx.z==1 ? T1 : T2;
  __shared__ float tile[32][33];
  const u32 k0 = blockIdx.x*32u, n0 = blockIdx.y*32u;
  const int t = threadIdx.x;
  const int r = t >> 3, c4 = (t & 7) * 4;
  f32x4 v = *reinterpret_cast<const f32x4*>(W + (size_t)(k0 + r)*N + n0 + c4);
  tile[r][c4+0]=v[0]; tile[r][c4+1]=v[1]; tile[r][c4+2]=v[2]; tile[r][c4+3]=v[3];
  __syncthreads();
  union { f16_t x[4]; uint64_t u; } pk;
  #pragma unroll
  for (int j=0;j<4;++j) pk.x[j] = (f16_t)tile[c4+j][r];
  *reinterpret_cast<uint64_t*>(WT + (size_t)(n0 + r)*K + k0 + c4) = pk.u;
}

// ---------------- GEMM: C = A * B^T (+bias), z-batched, runtime mode ----------------
// mode 0: f32 out plain. mode 1: f16 head layout ((b*16+h)*1024+s)*64+d.
// mode 2: f16 VT layout ((m>>10)*ldc+n)*1024+(m&1023). mode 3: f16 plain.
struct GArg { const void* A; const void* Bt; const float* bias; void* C; u32 ldc; int mode; };

__global__ __launch_bounds__(256, 2)
void gemm_bt(GArg g0, GArg g1, GArg g2, u32 lda, u32 ldb, u32 K)
{
  __shared__ char As[2][16384];
  __shared__ char Bs[2][16384];
  GArg g = blockIdx.z==0 ? g0 : blockIdx.z==1 ? g1 : g2;
  const int tid = threadIdx.x, lane = tid & 63, wid = tid >> 6;
  const int wr = wid >> 1, wc = wid & 1;
  const u32 bn = blockIdx.x * 128u, bm = blockIdx.y * 128u;
  const char* Ab = (const char*)((const f16_t*)g.A + (size_t)bm * lda);
  const char* Bb = (const char*)((const f16_t*)g.Bt + (size_t)bn * ldb);
  const u32 ldaB = lda*2u, ldbB = ldb*2u;

  f32x4 acc[4][4] = {};
  const int nt = (int)(K >> 6);

  stage_swz<16384,128,256>(Ab, ldaB, As[0], tid);
  stage_swz<16384,128,256>(Bb, ldbB, Bs[0], tid);
  __syncthreads();

  for (int t = 0; t < nt; ++t){
    if (t + 1 < nt){
      stage_swz<16384,128,256>(Ab + (size_t)(t+1)*128, ldaB, As[(t+1)&1], tid);
      stage_swz<16384,128,256>(Bb + (size_t)(t+1)*128, ldbB, Bs[(t+1)&1], tid);
    }
    const char* as = As[t&1]; const char* bs = Bs[t&1];
    f16x8 af[4][2], bf[4][2];
    #pragma unroll
    for (int mi=0; mi<4; ++mi)
      #pragma unroll
      for (int ks=0; ks<2; ++ks)
        af[mi][ks] = frag_ld(as, (u32)(wr*64 + mi*16 + (lane&15)), 128u, (u32)(ks*64 + ((lane>>4)<<4)));
    #pragma unroll
    for (int ni=0; ni<4; ++ni)
      #pragma unroll
      for (int ks=0; ks<2; ++ks)
        bf[ni][ks] = frag_ld(bs, (u32)(wc*64 + ni*16 + (lane&15)), 128u, (u32)(ks*64 + ((lane>>4)<<4)));
    #pragma unroll
    for (int mi=0; mi<4; ++mi)
      #pragma unroll
      for (int ni=0; ni<4; ++ni)
        #pragma unroll
        for (int ks=0; ks<2; ++ks)
          acc[mi][ni] = mfma16(af[mi][ks], bf[ni][ks], acc[mi][ni]);
    __syncthreads();
  }

  float bv[4];
  #pragma unroll
  for (int ni=0; ni<4; ++ni) bv[ni] = g.bias[bn + wc*64 + ni*16 + (lane&15)];

  #pragma unroll
  for (int mi=0; mi<4; ++mi){
    #pragma unroll
    for (int ni=0; ni<4; ++ni){
      u32 n  = bn + (u32)(wc*64 + ni*16 + (lane&15));
      u32 m0 = bm + (u32)(wr*64 + mi*16 + ((lane>>4)<<2));
      if (g.mode == 0){
        float* C = (float*)g.C;
        #pragma unroll
        for (int r=0;r<4;++r) C[(size_t)(m0+r)*g.ldc + n] = acc[mi][ni][r] + bv[ni];
      } else if (g.mode == 1){
        f16_t* C = (f16_t*)g.C;
        #pragma unroll
        for (int r=0;r<4;++r){
          u32 m = m0 + r;
          size_t idx = (((size_t)(m>>10)*16 + (n>>6))*1024 + (m&1023))*64 + (n&63);
          C[idx] = (f16_t)(acc[mi][ni][r] + bv[ni]);
        }
      } else if (g.mode == 2){
        f16_t* C = (f16_t*)g.C;
        size_t idx0 = ((size_t)(m0>>10)*g.ldc + n)*1024 + (m0 & 1023);
        union { f16_t v[4]; uint64_t u; } pk;
        #pragma unroll
        for (int r=0;r<4;++r) pk.v[r] = (f16_t)(acc[mi][ni][r] + bv[ni]);
        *reinterpret_cast<uint64_t*>(C + idx0) = pk.u;
      } else {
        f16_t* C = (f16_t*)g.C;
        #pragma unroll
        for (int r=0;r<4;++r) C[(size_t)(m0+r)*g.ldc + n] = (f16_t)(acc[mi][ni][r] + bv[ni]);
      }
    }
  }
}

// ---------------- attention pass 1: row sums of exp2 (fixed-max softmax) ----------------
// S^T form: block = 128 q-cols x S k-rows, chunks of 64 k. 8 waves: wr=k-half, wc=q-quarter.
template<int D, int BSHIFT, int SCALEBIT>
__global__ __launch_bounds__(512)
void attn_pass1(const f16_t* __restrict__ Qg, const f16_t* __restrict__ Kg,
                const float* __restrict__ mbias, float* __restrict__ statR)
{
  constexpr int S = 1024, KCH = 64;
  constexpr u32 ROWB = D*2;
  __shared__ char Qs[128*D*2];
  __shared__ char Ks[2][KCH*D*2];
  __shared__ float wsum[2][128];

  const int tid = threadIdx.x, lane = tid & 63, wid = tid >> 6;
  const int wr = wid >> 2, wc = wid & 3;
  const u32 qt = blockIdx.x, batch = blockIdx.y;
  const float scale = SCALEBIT ? 0.1803368801111244f : 1.4426950408889634f; // (1/8)*log2e : log2e
  const f16_t* qb = Qg + ((size_t)batch*S + (size_t)qt*128)*D;
  const f16_t* kb = Kg + (size_t)batch*S*D;
  const float* mbb = mbias + (size_t)(batch >> BSHIFT)*S;

  stage_swz<128*D*2, (int)ROWB, 512>((const char*)qb, ROWB, Qs, tid);
  stage_swz<KCH*D*2, (int)ROWB, 512>((const char*)kb, ROWB, Ks[0], tid);
  __syncthreads();

  float sacc[2] = {0.0f, 0.0f};
  constexpr int NCH = S / KCH;
  for (int ch = 0; ch < NCH; ++ch){
    if (ch + 1 < NCH)
      stage_swz<KCH*D*2, (int)ROWB, 512>((const char*)(kb + (size_t)(ch+1)*KCH*D), ROWB, Ks[(ch+1)&1], tid);
    const char* ks = Ks[ch&1];

    f32x4 mb[2];
    #pragma unroll
    for (int mi=0; mi<2; ++mi)
      mb[mi] = *reinterpret_cast<const f32x4*>(mbb + ch*KCH + wr*32 + mi*16 + ((lane>>4)<<2));

    f32x4 acc[2][2] = {};
    #pragma unroll
    for (int ksl=0; ksl<D/32; ++ksl){
      f16x8 af[2], bf[2];
      #pragma unroll
      for (int mi=0; mi<2; ++mi)
        af[mi] = frag_ld(ks, (u32)(wr*32 + mi*16 + (lane&15)), ROWB, (u32)(ksl*64 + ((lane>>4)<<4)));
      #pragma unroll
      for (int ni=0; ni<2; ++ni)
        bf[ni] = frag_ld(Qs, (u32)(wc*32 + ni*16 + (lane&15)), ROWB, (u32)(ksl*64 + ((lane>>4)<<4)));
      #pragma unroll
      for (int mi=0; mi<2; ++mi)
        #pragma unroll
        for (int ni=0; ni<2; ++ni)
          acc[mi][ni] = mfma16(af[mi], bf[ni], acc[mi][ni]);
    }

    #pragma unroll
    for (int ni=0; ni<2; ++ni)
      #pragma unroll
      for (int mi=0; mi<2; ++mi)
        #pragma unroll
        for (int r=0;r<4;++r)
          sacc[ni] += fexp2(acc[mi][ni][r]*scale + mb[mi][r]);

    __syncthreads();
  }

  #pragma unroll
  for (int ni=0; ni<2; ++ni){
    float s = sacc[ni];
    s += __shfl_xor(s, 16);
    s += __shfl_xor(s, 32);
    sacc[ni] = s;
  }
  if (lane < 16){
    wsum[wr][wc*32 + lane]      = sacc[0];
    wsum[wr][wc*32 + 16 + lane] = sacc[1];
  }
  __syncthreads();
  if (tid < 128)
    statR[(size_t)batch*S + (size_t)qt*128 + tid] = 1.0f / (wsum[0][tid] + wsum[1][tid]);
}

// ---------------- attention pass 2: softmax write + fused PV ----------------
template<int D, int BSHIFT, int SCALEBIT>
__global__ __launch_bounds__(512)
void attn_pass2(const f16_t* __restrict__ Qg, const f16_t* __restrict__ Kg, const f16_t* __restrict__ Vtg,
                const float* __restrict__ mbias, const float* __restrict__ statR,
                float* __restrict__ attnOut,
                f16_t* __restrict__ xout, u32 xld, u32 xcolAdd)
{
  constexpr int S = 1024, KCH = 64;
  constexpr u32 ROWB = D*2;
  constexpr int MIPV = D/32;
  __shared__ char Qs[128*D*2];
  __shared__ char Ks[2][KCH*D*2];
  __shared__ char Vs[2][D*KCH*2];
  __shared__ float Pout[128*KCH];

  const int tid = threadIdx.x, lane = tid & 63, wid = tid >> 6;
  const int wr = wid >> 2, wc = wid & 3;
  const u32 qt = blockIdx.x, batch = blockIdx.y;
  const u32 bb = batch >> BSHIFT;
  const float scale = SCALEBIT ? 0.1803368801111244f : 1.4426950408889634f;
  const f16_t* qb = Qg + ((size_t)batch*S + (size_t)qt*128)*D;
  const f16_t* kb = Kg + (size_t)batch*S*D;
  const char* vtb = (const char*)(Vtg + (size_t)batch*D*S);
  const float* mbb = mbias + (size_t)bb*S;
  char* poutb = (char*)Pout;

  float rreg[2];
  #pragma unroll
  for (int ni=0; ni<2; ++ni){
    u32 q = qt*128u + (u32)(wc*32 + ni*16 + (lane&15));
    rreg[ni] = statR[(size_t)batch*S + q];
  }
  f32x4 accX[MIPV][2] = {};

  stage_swz<128*D*2, (int)ROWB, 512>((const char*)qb, ROWB, Qs, tid);
  stage_swz<KCH*D*2, (int)ROWB, 512>((const char*)kb, ROWB, Ks[0], tid);
  stage_swz<D*KCH*2, 128, 512>(vtb, (u32)(S*2), Vs[0], tid);
  __syncthreads();

  constexpr int NCH = S / KCH;
  for (int ch = 0; ch < NCH; ++ch){
    if (ch + 1 < NCH){
      stage_swz<KCH*D*2, (int)ROWB, 512>((const char*)(kb + (size_t)(ch+1)*KCH*D), ROWB, Ks[(ch+1)&1], tid);
      stage_swz<D*KCH*2, 128, 512>(vtb + (size_t)(ch+1)*KCH*2, (u32)(S*2), Vs[(ch+1)&1], tid);
    }
    const char* ks = Ks[ch&1];
    const char* vs = Vs[ch&1];

    f32x4 mb[2];
    #pragma unroll
    for (int mi=0; mi<2; ++mi)
      mb[mi] = *reinterpret_cast<const f32x4*>(mbb + ch*KCH + wr*32 + mi*16 + ((lane>>4)<<2));

    f32x4 acc[2][2] = {};
    #pragma unroll
    for (int ksl=0; ksl<D/32; ++ksl){
      f16x8 af[2], bf[2];
      #pragma unroll
      for (int mi=0; mi<2; ++mi)
        af[mi] = frag_ld(ks, (u32)(wr*32 + mi*16 + (lane&15)), ROWB, (u32)(ksl*64 + ((lane>>4)<<4)));
      #pragma unroll
      for (int ni=0; ni<2; ++ni)
        bf[ni] = frag_ld(Qs, (u32)(wc*32 + ni*16 + (lane&15)), ROWB, (u32)(ksl*64 + ((lane>>4)<<4)));
      #pragma unroll
      for (int mi=0; mi<2; ++mi)
        #pragma unroll
        for (int ni=0; ni<2; ++ni)
          acc[mi][ni] = mfma16(af[mi], bf[ni], acc[mi][ni]);
    }

    // p = exp2(e2) * r  ->  Pout[q][k] (swizzled)
    #pragma unroll
    for (int ni=0; ni<2; ++ni){
      u32 q = (u32)(wc*32 + ni*16 + (lane&15));
      #pragma unroll
      for (int mi=0; mi<2; ++mi){
        f32x4 pv;
        #pragma unroll
        for (int r=0;r<4;++r)
          pv[r] = fexp2(acc[mi][ni][r]*scale + mb[mi][r]) * rreg[ni];
        u32 k0b = (u32)(wr*32 + mi*16 + ((lane>>4)<<2)) * 4u;
        *reinterpret_cast<f32x4*>(poutb + (size_t)q*256 + (k0b ^ ((q&7u)<<4))) = pv;
      }
    }
    __syncthreads();

    // PV: x^T[d][q] += Vt[d][s] * P^T[s][q]
    #pragma unroll
    for (int ksl=0; ksl<2; ++ksl){
      f16x8 pb[2];
      #pragma unroll
      for (int ni=0; ni<2; ++ni){
        u32 q = (u32)(wc*32 + ni*16 + (lane&15));
        u32 kb0 = (u32)(ksl*128 + ((lane>>4)<<5));
        f32x4 p0 = *reinterpret_cast<const f32x4*>(poutb + (size_t)q*256 + ((kb0      ) ^ ((q&7u)<<4)));
        f32x4 p1 = *reinterpret_cast<const f32x4*>(poutb + (size_t)q*256 + ((kb0 + 16u) ^ ((q&7u)<<4)));
        f16x8 v;
        v[0]=(f16_t)p0[0]; v[1]=(f16_t)p0[1]; v[2]=(f16_t)p0[2]; v[3]=(f16_t)p0[3];
        v[4]=(f16_t)p1[0]; v[5]=(f16_t)p1[1]; v[6]=(f16_t)p1[2]; v[7]=(f16_t)p1[3];
        pb[ni] = v;
      }
      #pragma unroll
      for (int mi=0; mi<MIPV; ++mi){
        f16x8 vf = frag_ld(vs, (u32)(wr*(D/2) + mi*16 + (lane&15)), 128u, (u32)(ksl*64 + ((lane>>4)<<4)));
        #pragma unroll
        for (int ni=0; ni<2; ++ni)
          accX[mi][ni] = mfma16(vf, pb[ni], accX[mi][ni]);
      }
    }

    // coalesced attention store
    {
      u32 q2 = (u32)tid >> 2;
      float* abase = attnOut + (size_t)batch*S*S + ((size_t)qt*128 + q2)*S + (size_t)ch*KCH;
      #pragma unroll
      for (int j=0;j<4;++j){
        u32 kbyte = ((u32)(tid&3) + 4u*(u32)j)*16u;
        f32x4 v = *reinterpret_cast<const f32x4*>(poutb + (size_t)q2*256 + (kbyte ^ ((q2&7u)<<4)));
        *reinterpret_cast<f32x4*>(abase + (kbyte>>2)) = v;
      }
    }
    __syncthreads();
  }

  // write x^T to concat buffer
  u32 col0 = (batch & ((1u<<BSHIFT)-1u)) * (u32)D + xcolAdd;
  #pragma unroll
  for (int mi=0; mi<MIPV; ++mi){
    #pragma unroll
    for (int ni=0; ni<2; ++ni){
      u32 d = (u32)(wr*(D/2) + mi*16 + ((lane>>4)<<2));
      u32 q = qt*128u + (u32)(wc*32 + ni*16 + (lane&15));
      union { f16_t v[4]; uint64_t u; } pk;
      #pragma unroll
      for (int r=0;r<4;++r) pk.v[r] = (f16_t)accX[mi][ni][r];
      *reinterpret_cast<uint64_t*>(xout + ((size_t)bb*S + q)*xld + col0 + d) = pk.u;
    }
  }
}

// ---------------- launch ----------------
extern "C" void kernel_launch(void* const* d_in, const int* in_sizes, int n_in,
                              void* d_out, int out_size, void* d_ws, size_t ws_size,
                              hipStream_t stream)
{
  const float* query = (const float*)d_in[0];
  const float* key   = (const float*)d_in[1];
  const float* value = (const float*)d_in[2];
  const float* x_rsa = (const float*)d_in[3];
  const int*   mask  = (const int*)d_in[4];
  const int*   rmask = (const int*)d_in[5];
  const float* Wq = (const float*)d_in[6];  const float* bq = (const float*)d_in[7];
  const float* Wk = (const float*)d_in[8];  const float* bk = (const float*)d_in[9];
  const float* Wv = (const float*)d_in[10]; const float* bv = (const float*)d_in[11];
  const float* Wsk= (const float*)d_in[12]; const float* bsk= (const float*)d_in[13];
  const float* Wsv= (const float*)d_in[14]; const float* bsv= (const float*)d_in[15];
  const float* Wo = (const float*)d_in[16]; const float* bo = (const float*)d_in[17];

  char* ws = (char*)d_ws;
  size_t off = 0;
  auto alloc = [&](size_t bytes)->char*{ char* p = ws + off; off += (bytes + 255) & ~(size_t)255; return p; };

  f16_t* q16  = (f16_t*)alloc(16777216);
  f16_t* k16  = (f16_t*)alloc(16777216);
  f16_t* v16  = (f16_t*)alloc(16777216);
  f16_t* xrf  = (f16_t*)alloc(2097152);
  f16_t* wqT  = (f16_t*)alloc(2097152);
  f16_t* wkT  = (f16_t*)alloc(2097152);
  f16_t* wvT  = (f16_t*)alloc(2097152);
  f16_t* wskT = (f16_t*)alloc(262144);
  f16_t* wsvT = (f16_t*)alloc(262144);
  f16_t* woT  = (f16_t*)alloc(2359296);
  f16_t* Qh   = (f16_t*)alloc(16777216);
  f16_t* Kh   = (f16_t*)alloc(16777216);
  f16_t* Vth  = (f16_t*)alloc(16777216);
  f16_t* strK = (f16_t*)alloc(2097152);
  f16_t* strVt= (f16_t*)alloc(2097152);
  f16_t* conc = (f16_t*)alloc(18874368);
  float* stRm = (float*)alloc(524288);
  float* stRr = (float*)alloc(32768);
  float* mbias= (float*)alloc(32768);
  float* rbias= (float*)alloc(32768);

  // prep: all converts + mask biases in one launch
  prep_all<<<12832,256,0,stream>>>(query, key, value, x_rsa, mask, rmask,
                                   q16, k16, v16, xrf, mbias, rbias);
  // weight transposes (z-batched)
  transpose_cvt<<<dim3(32,32,3),256,0,stream>>>(Wq, Wk, Wv, wqT, wkT, wvT, 1024, 1024);
  transpose_cvt<<<dim3(32,4,2), 256,0,stream>>>(Wsk, Wsv, Wsv, wskT, wsvT, wsvT, 1024, 128);
  transpose_cvt<<<dim3(36,32,1),256,0,stream>>>(Wo, Wo, Wo, woT, woT, woT, 1152, 1024);

  // Q/K/V projections in one z-batched launch
  {
    GArg gq{q16, wqT, bq, Qh,  0,    1};
    GArg gk{k16, wkT, bk, Kh,  0,    1};
    GArg gv{v16, wvT, bv, Vth, 1024, 2};
    gemm_bt<<<dim3(8,64,3),256,0,stream>>>(gq, gk, gv, 1024, 1024, 1024);
  }
  // strK / strV projections
  {
    GArg gk{k16, wskT, bsk, strK,  128, 3};
    GArg gv{v16, wsvT, bsv, strVt, 128, 2};
    gemm_bt<<<dim3(1,64,2),256,0,stream>>>(gk, gv, gv, 1024, 1024, 1024);
  }

  // attention stats (row sums only)
  attn_pass1<64,4,1> <<<dim3(8,128),512,0,stream>>>(Qh,  Kh,   mbias, stRm);
  attn_pass1<128,0,0><<<dim3(8,8),  512,0,stream>>>(xrf, strK, rbias, stRr);

  float* outp  = (float*)d_out;
  float* attnp = outp + 8388608;
  float* rsap  = outp + 8388608 + 134217728;

  // attention pass2 (softmax out + PV into concat)
  attn_pass2<64,4,1> <<<dim3(8,128),512,0,stream>>>(Qh,  Kh,   Vth,   mbias, stRm, attnp, conc, 1152, 0);
  attn_pass2<128,0,0><<<dim3(8,8),  512,0,stream>>>(xrf, strK, strVt, rbias, stRr, rsap,  conc, 1152, 1024);

  // output projection
  {
    GArg go{conc, woT, bo, outp, 1024, 0};
    gemm_bt<<<dim3(8,64,1),256,0,stream>>>(go, go, go, 1152, 1152, 1152);
  }

  (void)in_sizes; (void)n_in; (void)out_size; (void)ws_size;
}

// Round 3
// 397.712 us; speedup vs baseline: 1.4200x; 1.0780x over previous
//
#include <hip/hip_runtime.h>
#include <stdint.h>

typedef unsigned int u32;
typedef _Float16 f16_t;

typedef _Float16 f16x8 __attribute__((ext_vector_type(8)));
typedef float    f32x4 __attribute__((ext_vector_type(4)));

__device__ __forceinline__ f32x4 mfma16(f16x8 a, f16x8 b, f32x4 c){
  return __builtin_amdgcn_mfma_f32_16x16x32_f16(a, b, c, 0, 0, 0);
}
__device__ __forceinline__ float fexp2(float x){ return __builtin_amdgcn_exp2f(x); }

// async global->LDS, 16B per lane; LDS dest is wave-uniform base + lane*16
__device__ __forceinline__ void gl_lds16(const void* g, void* l){
  typedef const __attribute__((address_space(1))) void* gasp;
  typedef __attribute__((address_space(3))) void* lasp;
  gasp gp = reinterpret_cast<gasp>(reinterpret_cast<uintptr_t>(g));
  lasp lp = reinterpret_cast<lasp>(static_cast<u32>(reinterpret_cast<uintptr_t>(l)));
  __builtin_amdgcn_global_load_lds(gp, lp, 16, 0, 0);
}

// Stage a [NROWS][ROWB bytes] tile: LDS[row][c'] = G[row][c' ^ sw(row)].
// Swizzle mask adapts to row size: sw = (row & (ROWB/16-1)) << 4.
template<int NBYTES, int ROWB, int NT>
__device__ __forceinline__ void stage_swz(const char* gbase, u32 gstrideB, char* lds, int tid){
  const u32 lane = (u32)(tid & 63);
  #pragma unroll
  for (int j = 0; j < NBYTES/(NT*16); ++j){
    u32 o   = (u32)(j*NT + tid) * 16u;
    u32 row = o / (u32)ROWB;
    u32 col = (o % (u32)ROWB) ^ ((row & ((u32)(ROWB>>4)-1u)) << 4);
    gl_lds16(gbase + (size_t)row * gstrideB + col, lds + (o - lane*16u));
  }
}

template<int ROWB>
__device__ __forceinline__ u32 swzb(u32 row, u32 col){
  return col ^ ((row & ((u32)(ROWB>>4)-1u)) << 4);
}

template<int ROWB>
__device__ __forceinline__ f16x8 frag_ld(const char* lds, u32 row, u32 kbyte){
  return *reinterpret_cast<const f16x8*>(lds + (size_t)row*ROWB + swzb<ROWB>(row, kbyte));
}

// ---------------- prep: converts + mask bias + weight transposes, one launch ----------------
__device__ __forceinline__ void cvt8(const float* __restrict__ in, f16_t* __restrict__ out, u32 i){
  const f32x4* p = reinterpret_cast<const f32x4*>(in) + 2*(size_t)i;
  f32x4 a = p[0], b = p[1];
  f16x8 v;
  v[0]=(f16_t)a[0]; v[1]=(f16_t)a[1]; v[2]=(f16_t)a[2]; v[3]=(f16_t)a[3];
  v[4]=(f16_t)b[0]; v[5]=(f16_t)b[1]; v[6]=(f16_t)b[2]; v[7]=(f16_t)b[3];
  *(reinterpret_cast<f16x8*>(out) + i) = v;
}

__global__ void prep_all(const float* __restrict__ q, const float* __restrict__ k,
                         const float* __restrict__ v, const float* __restrict__ xr,
                         const int* __restrict__ mask, const int* __restrict__ rmask,
                         f16_t* __restrict__ qo, f16_t* __restrict__ ko,
                         f16_t* __restrict__ vo, f16_t* __restrict__ xo,
                         float* __restrict__ mb, float* __restrict__ rb,
                         const float* __restrict__ Wq, const float* __restrict__ Wk,
                         const float* __restrict__ Wv, const float* __restrict__ Wsk,
                         const float* __restrict__ Wsv, const float* __restrict__ Wo,
                         f16_t* __restrict__ wqT, f16_t* __restrict__ wkT, f16_t* __restrict__ wvT,
                         f16_t* __restrict__ wskT, f16_t* __restrict__ wsvT, f16_t* __restrict__ woT)
{
  __shared__ float tile[32][33];
  u32 b = blockIdx.x;
  if (b < 12288u){
    const float* in; f16_t* out; u32 base;
    if (b < 4096u){ in=q; out=qo; base=0u; }
    else if (b < 8192u){ in=k; out=ko; base=4096u; }
    else { in=v; out=vo; base=8192u; }
    cvt8(in, out, (b-base)*256u + threadIdx.x);
  } else if (b < 12800u){
    cvt8(xr, xo, (b-12288u)*256u + threadIdx.x);
  } else if (b < 12832u){
    u32 i = (b-12800u)*256u + threadIdx.x;
    int m = mask[i]; int r = rmask[i];
    mb[i] = m ? 0.0f : -1.0e9f;          // log2-domain bias: exp2(-1e9)=0
    rb[i] = (m && r) ? 0.0f : -1.0e9f;
  } else {
    u32 t = b - 12832u;
    const float* W; f16_t* WT; u32 K, N, i, j;
    if (t < 3072u){
      u32 w = t >> 10, l = t & 1023u;
      W = w==0 ? Wq : w==1 ? Wk : Wv;
      WT = w==0 ? wqT : w==1 ? wkT : wvT;
      K = 1024u; N = 1024u; i = l & 31u; j = l >> 5;
    } else if (t < 3328u){
      u32 l = t - 3072u;
      W  = l < 128u ? Wsk : Wsv;
      WT = l < 128u ? wskT : wsvT;
      l &= 127u;
      K = 1024u; N = 128u; i = l & 31u; j = l >> 5;
    } else {
      u32 l = t - 3328u;
      W = Wo; WT = woT; K = 1152u; N = 1024u; i = l % 36u; j = l / 36u;
    }
    const u32 k0 = i*32u, n0 = j*32u;
    const int tt = threadIdx.x;
    const int r = tt >> 3, c4 = (tt & 7) * 4;
    f32x4 val = *reinterpret_cast<const f32x4*>(W + (size_t)(k0 + r)*N + n0 + c4);
    tile[r][c4+0]=val[0]; tile[r][c4+1]=val[1]; tile[r][c4+2]=val[2]; tile[r][c4+3]=val[3];
    __syncthreads();
    union { f16_t x[4]; uint64_t u; } pk;
    #pragma unroll
    for (int jj=0;jj<4;++jj) pk.x[jj] = (f16_t)tile[c4+jj][r];
    *reinterpret_cast<uint64_t*>(WT + (size_t)(n0 + r)*K + k0 + c4) = pk.u;
  }
}

// ---------------- GEMM: C = A * B^T (+bias) ----------------
// mode 0: f32 out plain (swapped). mode 1: f16 head layout (swapped).
// mode 2: f16 VT layout ((m>>10)*ldc+n)*1024+(m&1023), pack along m (unswapped).
// mode 3: f16 plain (swapped).
struct GArg { const f16_t* A; const f16_t* Bt; const float* bias; void* C; u32 lda, ldb, ldc, K; int mode; };
struct GPack { GArg g[5]; int single; };

__global__ __launch_bounds__(256, 2)
void gemm_bt(GPack p)
{
  __shared__ char As[2][16384];
  __shared__ char Bs[2][16384];
  GArg g; u32 bn;
  const u32 bm = blockIdx.y * 128u;
  if (p.single >= 0){ g = p.g[p.single]; bn = blockIdx.x*128u; }
  else if (blockIdx.z == 0u){ if (blockIdx.x >= 2u) return; g = p.g[3u+blockIdx.x]; bn = 0u; }
  else { g = p.g[blockIdx.z-1u]; bn = blockIdx.x*128u; }

  const int tid = threadIdx.x, lane = tid & 63, wid = tid >> 6;
  const int wr = wid >> 1, wc = wid & 1;
  const char* Ab = (const char*)(g.A + (size_t)bm * g.lda);
  const char* Bb = (const char*)(g.Bt + (size_t)bn * g.ldb);
  const u32 ldaB = g.lda*2u, ldbB = g.ldb*2u;
  const bool swp = (g.mode != 2);

  f32x4 acc[4][4] = {};
  const int nt = (int)(g.K >> 6);

  stage_swz<16384,128,256>(Ab, ldaB, As[0], tid);
  stage_swz<16384,128,256>(Bb, ldbB, Bs[0], tid);
  __syncthreads();

  for (int t = 0; t < nt; ++t){
    if (t + 1 < nt){
      stage_swz<16384,128,256>(Ab + (size_t)(t+1)*128, ldaB, As[(t+1)&1], tid);
      stage_swz<16384,128,256>(Bb + (size_t)(t+1)*128, ldbB, Bs[(t+1)&1], tid);
    }
    const char* as = As[t&1]; const char* bs = Bs[t&1];
    f16x8 af[4][2], bf[4][2];
    #pragma unroll
    for (int mi=0; mi<4; ++mi)
      #pragma unroll
      for (int ks=0; ks<2; ++ks)
        af[mi][ks] = frag_ld<128>(as, (u32)(wr*64 + mi*16 + (lane&15)), (u32)(ks*64 + ((lane>>4)<<4)));
    #pragma unroll
    for (int ni=0; ni<4; ++ni)
      #pragma unroll
      for (int ks=0; ks<2; ++ks)
        bf[ni][ks] = frag_ld<128>(bs, (u32)(wc*64 + ni*16 + (lane&15)), (u32)(ks*64 + ((lane>>4)<<4)));
    if (swp){
      #pragma unroll
      for (int mi=0; mi<4; ++mi)
        #pragma unroll
        for (int ni=0; ni<4; ++ni)
          #pragma unroll
          for (int ks=0; ks<2; ++ks)
            acc[mi][ni] = mfma16(bf[ni][ks], af[mi][ks], acc[mi][ni]);
    } else {
      #pragma unroll
      for (int mi=0; mi<4; ++mi)
        #pragma unroll
        for (int ni=0; ni<4; ++ni)
          #pragma unroll
          for (int ks=0; ks<2; ++ks)
            acc[mi][ni] = mfma16(af[mi][ks], bf[ni][ks], acc[mi][ni]);
    }
    __syncthreads();
  }

  if (g.mode == 2){
    // unswapped: lane holds col n fixed, rows m0..m0+3 -> pack along m
    float bv[4];
    #pragma unroll
    for (int ni=0; ni<4; ++ni) bv[ni] = g.bias[bn + wc*64 + ni*16 + (lane&15)];
    f16_t* C = (f16_t*)g.C;
    #pragma unroll
    for (int mi=0; mi<4; ++mi){
      #pragma unroll
      for (int ni=0; ni<4; ++ni){
        u32 n  = bn + (u32)(wc*64 + ni*16 + (lane&15));
        u32 m0 = bm + (u32)(wr*64 + mi*16 + ((lane>>4)<<2));
        size_t idx0 = ((size_t)(m0>>10)*g.ldc + n)*1024 + (m0 & 1023);
        union { f16_t v[4]; uint64_t u; } pk;
        #pragma unroll
        for (int r=0;r<4;++r) pk.v[r] = (f16_t)(acc[mi][ni][r] + bv[ni]);
        *reinterpret_cast<uint64_t*>(C + idx0) = pk.u;
      }
    }
  } else {
    // swapped: lane holds row m fixed, cols n0..n0+3 -> packed stores along n
    f32x4 bf4[4];
    #pragma unroll
    for (int ni=0; ni<4; ++ni)
      bf4[ni] = *reinterpret_cast<const f32x4*>(g.bias + bn + wc*64 + ni*16 + ((lane>>4)<<2));
    #pragma unroll
    for (int mi=0; mi<4; ++mi){
      u32 m = bm + (u32)(wr*64 + mi*16 + (lane&15));
      #pragma unroll
      for (int ni=0; ni<4; ++ni){
        u32 n0 = bn + (u32)(wc*64 + ni*16 + ((lane>>4)<<2));
        if (g.mode == 0){
          float* C = (float*)g.C;
          f32x4 v = acc[mi][ni] + bf4[ni];
          *reinterpret_cast<f32x4*>(C + (size_t)m*g.ldc + n0) = v;
        } else if (g.mode == 1){
          f16_t* C = (f16_t*)g.C;
          size_t idx = (((size_t)(m>>10)*16 + (n0>>6))*1024 + (m&1023))*64 + (n0&63);
          union { f16_t v[4]; uint64_t u; } pk;
          #pragma unroll
          for (int r=0;r<4;++r) pk.v[r] = (f16_t)(acc[mi][ni][r] + bf4[ni][r]);
          *reinterpret_cast<uint64_t*>(C + idx) = pk.u;
        } else {
          f16_t* C = (f16_t*)g.C;
          union { f16_t v[4]; uint64_t u; } pk;
          #pragma unroll
          for (int r=0;r<4;++r) pk.v[r] = (f16_t)(acc[mi][ni][r] + bf4[ni][r]);
          *reinterpret_cast<uint64_t*>(C + (size_t)m*g.ldc + n0) = pk.u;
        }
      }
    }
  }
}

// ---------------- attention pass 1 body: row sums of exp2 (fixed-max softmax) ----------------
template<int D, int KCH, int BSHIFT, int SCALEBIT>
__device__ __forceinline__ void pass1_body(char* smem,
    const f16_t* __restrict__ Qg, const f16_t* __restrict__ Kg,
    const float* __restrict__ mbias, float* __restrict__ statR,
    const int tid, const u32 qt, const u32 batch)
{
  constexpr int S = 1024;
  constexpr int ROWB = D*2;
  constexpr int MI = KCH/32;
  char* Qs  = smem;
  char* Ks0 = smem + 128*ROWB;
  char* Ks1 = Ks0 + KCH*ROWB;
  float* wsum = (float*)(Ks1 + KCH*ROWB);   // [256]

  const int lane = tid & 63, wid = tid >> 6;
  const int wr = wid >> 2, wc = wid & 3;
  const float scale = SCALEBIT ? 0.1803368801111244f : 1.4426950408889634f;
  const f16_t* qb = Qg + ((size_t)batch*S + (size_t)qt*128)*D;
  const f16_t* kb = Kg + (size_t)batch*S*D;
  const float* mbb = mbias + (size_t)(batch >> BSHIFT)*S;

  stage_swz<128*ROWB, ROWB, 512>((const char*)qb, ROWB, Qs, tid);
  stage_swz<KCH*ROWB, ROWB, 512>((const char*)kb, ROWB, Ks0, tid);
  __syncthreads();

  float sacc[2] = {0.0f, 0.0f};
  constexpr int NCH = S / KCH;
  for (int ch = 0; ch < NCH; ++ch){
    if (ch + 1 < NCH)
      stage_swz<KCH*ROWB, ROWB, 512>((const char*)(kb + (size_t)(ch+1)*KCH*D), ROWB, ((ch+1)&1)?Ks1:Ks0, tid);
    const char* ks = (ch&1) ? Ks1 : Ks0;

    f32x4 mb[MI];
    #pragma unroll
    for (int mi=0; mi<MI; ++mi)
      mb[mi] = *reinterpret_cast<const f32x4*>(mbb + ch*KCH + wr*(KCH/2) + mi*16 + ((lane>>4)<<2));

    f32x4 acc[MI][2] = {};
    #pragma unroll
    for (int ksl=0; ksl<D/32; ++ksl){
      f16x8 af[MI], bf[2];
      #pragma unroll
      for (int mi=0; mi<MI; ++mi)
        af[mi] = frag_ld<ROWB>(ks, (u32)(wr*(KCH/2) + mi*16 + (lane&15)), (u32)(ksl*64 + ((lane>>4)<<4)));
      #pragma unroll
      for (int ni=0; ni<2; ++ni)
        bf[ni] = frag_ld<ROWB>(Qs, (u32)(wc*32 + ni*16 + (lane&15)), (u32)(ksl*64 + ((lane>>4)<<4)));
      #pragma unroll
      for (int mi=0; mi<MI; ++mi)
        #pragma unroll
        for (int ni=0; ni<2; ++ni)
          acc[mi][ni] = mfma16(af[mi], bf[ni], acc[mi][ni]);
    }

    #pragma unroll
    for (int ni=0; ni<2; ++ni)
      #pragma unroll
      for (int mi=0; mi<MI; ++mi)
        #pragma unroll
        for (int r=0;r<4;++r)
          sacc[ni] += fexp2(acc[mi][ni][r]*scale + mb[mi][r]);

    __syncthreads();
  }

  #pragma unroll
  for (int ni=0; ni<2; ++ni){
    float s = sacc[ni];
    s += __shfl_xor(s, 16);
    s += __shfl_xor(s, 32);
    sacc[ni] = s;
  }
  if (lane < 16){
    wsum[wr*128 + wc*32 + lane]      = sacc[0];
    wsum[wr*128 + wc*32 + 16 + lane] = sacc[1];
  }
  __syncthreads();
  if (tid < 128)
    statR[(size_t)batch*S + (size_t)qt*128 + tid] = 1.0f / (wsum[tid] + wsum[128 + tid]);
}

// ---------------- attention pass 2 body: softmax write + fused PV ----------------
template<int D, int KCH, int BSHIFT, int SCALEBIT>
__device__ __forceinline__ void pass2_body(char* smem,
    const f16_t* __restrict__ Qg, const f16_t* __restrict__ Kg, const f16_t* __restrict__ Vtg,
    const float* __restrict__ mbias, const float* __restrict__ statR,
    float* __restrict__ attnOut, f16_t* __restrict__ xout, u32 xld, u32 xcolAdd,
    const int tid, const u32 qt, const u32 batch)
{
  constexpr int S = 1024;
  constexpr int ROWB = D*2;
  constexpr int ROWBV = KCH*2;
  constexpr int PROW = KCH*4;
  constexpr int MI = KCH/32;
  constexpr int MIPV = D/32;
  char* Qs  = smem;
  char* Ks0 = Qs + 128*ROWB;
  char* Ks1 = Ks0 + KCH*ROWB;
  char* Vs0 = Ks1 + KCH*ROWB;
  char* Vs1 = Vs0 + D*KCH*2;
  char* poutb = Vs1 + D*KCH*2;            // 128*KCH f32

  const int lane = tid & 63, wid = tid >> 6;
  const int wr = wid >> 2, wc = wid & 3;
  const u32 bb = batch >> BSHIFT;
  const float scale = SCALEBIT ? 0.1803368801111244f : 1.4426950408889634f;
  const f16_t* qb = Qg + ((size_t)batch*S + (size_t)qt*128)*D;
  const f16_t* kb = Kg + (size_t)batch*S*D;
  const char* vtb = (const char*)(Vtg + (size_t)batch*D*S);
  const float* mbb = mbias + (size_t)bb*S;

  float rreg[2];
  #pragma unroll
  for (int ni=0; ni<2; ++ni){
    u32 q = qt*128u + (u32)(wc*32 + ni*16 + (lane&15));
    rreg[ni] = statR[(size_t)batch*S + q];
  }
  f32x4 accX[MIPV][2] = {};

  stage_swz<128*ROWB, ROWB, 512>((const char*)qb, ROWB, Qs, tid);
  stage_swz<KCH*ROWB, ROWB, 512>((const char*)kb, ROWB, Ks0, tid);
  stage_swz<D*KCH*2, ROWBV, 512>(vtb, (u32)(S*2), Vs0, tid);
  __syncthreads();

  constexpr int NCH = S / KCH;
  for (int ch = 0; ch < NCH; ++ch){
    if (ch + 1 < NCH){
      stage_swz<KCH*ROWB, ROWB, 512>((const char*)(kb + (size_t)(ch+1)*KCH*D), ROWB, ((ch+1)&1)?Ks1:Ks0, tid);
      stage_swz<D*KCH*2, ROWBV, 512>(vtb + (size_t)(ch+1)*KCH*2, (u32)(S*2), ((ch+1)&1)?Vs1:Vs0, tid);
    }
    const char* ks = (ch&1) ? Ks1 : Ks0;
    const char* vs = (ch&1) ? Vs1 : Vs0;

    f32x4 mb[MI];
    #pragma unroll
    for (int mi=0; mi<MI; ++mi)
      mb[mi] = *reinterpret_cast<const f32x4*>(mbb + ch*KCH + wr*(KCH/2) + mi*16 + ((lane>>4)<<2));

    f32x4 acc[MI][2] = {};
    #pragma unroll
    for (int ksl=0; ksl<D/32; ++ksl){
      f16x8 af[MI], bf[2];
      #pragma unroll
      for (int mi=0; mi<MI; ++mi)
        af[mi] = frag_ld<ROWB>(ks, (u32)(wr*(KCH/2) + mi*16 + (lane&15)), (u32)(ksl*64 + ((lane>>4)<<4)));
      #pragma unroll
      for (int ni=0; ni<2; ++ni)
        bf[ni] = frag_ld<ROWB>(Qs, (u32)(wc*32 + ni*16 + (lane&15)), (u32)(ksl*64 + ((lane>>4)<<4)));
      #pragma unroll
      for (int mi=0; mi<MI; ++mi)
        #pragma unroll
        for (int ni=0; ni<2; ++ni)
          acc[mi][ni] = mfma16(af[mi], bf[ni], acc[mi][ni]);
    }

    // p = exp2(e2) * r  ->  Pout[q][k] (swizzled)
    #pragma unroll
    for (int ni=0; ni<2; ++ni){
      u32 q = (u32)(wc*32 + ni*16 + (lane&15));
      #pragma unroll
      for (int mi=0; mi<MI; ++mi){
        f32x4 pv;
        #pragma unroll
        for (int r=0;r<4;++r)
          pv[r] = fexp2(acc[mi][ni][r]*scale + mb[mi][r]) * rreg[ni];
        u32 k0b = (u32)(wr*(KCH/2) + mi*16 + ((lane>>4)<<2)) * 4u;
        *reinterpret_cast<f32x4*>(poutb + (size_t)q*PROW + swzb<PROW>(q, k0b)) = pv;
      }
    }
    __syncthreads();

    // PV: x^T[d][q] += Vt[d][s] * P^T[s][q]
    #pragma unroll
    for (int ksl=0; ksl<KCH/32; ++ksl){
      f16x8 pb[2];
      #pragma unroll
      for (int ni=0; ni<2; ++ni){
        u32 q = (u32)(wc*32 + ni*16 + (lane&15));
        u32 kb0 = (u32)(ksl*128 + ((lane>>4)<<5));
        f32x4 p0 = *reinterpret_cast<const f32x4*>(poutb + (size_t)q*PROW + swzb<PROW>(q, kb0));
        f32x4 p1 = *reinterpret_cast<const f32x4*>(poutb + (size_t)q*PROW + swzb<PROW>(q, kb0 + 16u));
        f16x8 v;
        v[0]=(f16_t)p0[0]; v[1]=(f16_t)p0[1]; v[2]=(f16_t)p0[2]; v[3]=(f16_t)p0[3];
        v[4]=(f16_t)p1[0]; v[5]=(f16_t)p1[1]; v[6]=(f16_t)p1[2]; v[7]=(f16_t)p1[3];
        pb[ni] = v;
      }
      #pragma unroll
      for (int mi=0; mi<MIPV; ++mi){
        f16x8 vf = frag_ld<ROWBV>(vs, (u32)(wr*(D/2) + mi*16 + (lane&15)), (u32)(ksl*64 + ((lane>>4)<<4)));
        #pragma unroll
        for (int ni=0; ni<2; ++ni)
          accX[mi][ni] = mfma16(vf, pb[ni], accX[mi][ni]);
      }
    }

    // coalesced attention store
    {
      u32 q2 = (u32)tid >> 2;
      float* abase = attnOut + (size_t)batch*S*S + ((size_t)qt*128 + q2)*S + (size_t)ch*KCH;
      #pragma unroll
      for (int j=0; j<KCH/16; ++j){
        u32 kbyte = ((u32)(tid&3) + 4u*(u32)j)*16u;
        f32x4 v = *reinterpret_cast<const f32x4*>(poutb + (size_t)q2*PROW + swzb<PROW>(q2, kbyte));
        *reinterpret_cast<f32x4*>(abase + (kbyte>>2)) = v;
      }
    }
    __syncthreads();
  }

  // write x^T to concat buffer
  u32 col0 = (batch & ((1u<<BSHIFT)-1u)) * (u32)D + xcolAdd;
  #pragma unroll
  for (int mi=0; mi<MIPV; ++mi){
    #pragma unroll
    for (int ni=0; ni<2; ++ni){
      u32 d = (u32)(wr*(D/2) + mi*16 + ((lane>>4)<<2));
      u32 q = qt*128u + (u32)(wc*32 + ni*16 + (lane&15));
      union { f16_t v[4]; uint64_t u; } pk;
      #pragma unroll
      for (int r=0;r<4;++r) pk.v[r] = (f16_t)accX[mi][ni][r];
      *reinterpret_cast<uint64_t*>(xout + ((size_t)bb*S + q)*xld + col0 + d) = pk.u;
    }
  }
}

// ---------------- combined attention kernels (rsa blocks dispatched first) ----------------
__global__ __launch_bounds__(512)
void attn_pass1_all(const f16_t* __restrict__ Qh, const f16_t* __restrict__ Kh,
                    const float* __restrict__ mbias, float* __restrict__ stRm,
                    const f16_t* __restrict__ xrf, const f16_t* __restrict__ strK,
                    const float* __restrict__ rbias, float* __restrict__ stRr)
{
  __shared__ char smem[50176];
  const int tid = threadIdx.x;
  const u32 qt = blockIdx.x, y = blockIdx.y;
  if (y < 8u) pass1_body<128,32,0,0>(smem, xrf, strK, rbias, stRr, tid, qt, y);
  else        pass1_body<64, 64,4,1>(smem, Qh,  Kh,   mbias, stRm, tid, qt, y-8u);
}

__global__ __launch_bounds__(512)
void attn_pass2_all(const f16_t* __restrict__ Qh, const f16_t* __restrict__ Kh,
                    const f16_t* __restrict__ Vth, const float* __restrict__ mbias,
                    const float* __restrict__ stRm, float* __restrict__ attnp,
                    const f16_t* __restrict__ xrf, const f16_t* __restrict__ strK,
                    const f16_t* __restrict__ strVt, const float* __restrict__ rbias,
                    const float* __restrict__ stRr, float* __restrict__ rsap,
                    f16_t* __restrict__ conc)
{
  __shared__ char smem[81920];
  const int tid = threadIdx.x;
  const u32 qt = blockIdx.x, y = blockIdx.y;
  if (y < 8u) pass2_body<128,32,0,0>(smem, xrf, strK, strVt, rbias, stRr, rsap, conc, 1152u, 1024u, tid, qt, y);
  else        pass2_body<64, 64,4,1>(smem, Qh,  Kh,   Vth,   mbias, stRm, attnp, conc, 1152u, 0u,    tid, qt, y-8u);
}

// ---------------- launch ----------------
extern "C" void kernel_launch(void* const* d_in, const int* in_sizes, int n_in,
                              void* d_out, int out_size, void* d_ws, size_t ws_size,
                              hipStream_t stream)
{
  const float* query = (const float*)d_in[0];
  const float* key   = (const float*)d_in[1];
  const float* value = (const float*)d_in[2];
  const float* x_rsa = (const float*)d_in[3];
  const int*   mask  = (const int*)d_in[4];
  const int*   rmask = (const int*)d_in[5];
  const float* Wq = (const float*)d_in[6];  const float* bq = (const float*)d_in[7];
  const float* Wk = (const float*)d_in[8];  const float* bk = (const float*)d_in[9];
  const float* Wv = (const float*)d_in[10]; const float* bv = (const float*)d_in[11];
  const float* Wsk= (const float*)d_in[12]; const float* bsk= (const float*)d_in[13];
  const float* Wsv= (const float*)d_in[14]; const float* bsv= (const float*)d_in[15];
  const float* Wo = (const float*)d_in[16]; const float* bo = (const float*)d_in[17];

  char* ws = (char*)d_ws;
  size_t off = 0;
  auto alloc = [&](size_t bytes)->char*{ char* p = ws + off; off += (bytes + 255) & ~(size_t)255; return p; };

  f16_t* q16  = (f16_t*)alloc(16777216);
  f16_t* k16  = (f16_t*)alloc(16777216);
  f16_t* v16  = (f16_t*)alloc(16777216);
  f16_t* xrf  = (f16_t*)alloc(2097152);
  f16_t* wqT  = (f16_t*)alloc(2097152);
  f16_t* wkT  = (f16_t*)alloc(2097152);
  f16_t* wvT  = (f16_t*)alloc(2097152);
  f16_t* wskT = (f16_t*)alloc(262144);
  f16_t* wsvT = (f16_t*)alloc(262144);
  f16_t* woT  = (f16_t*)alloc(2359296);
  f16_t* Qh   = (f16_t*)alloc(16777216);
  f16_t* Kh   = (f16_t*)alloc(16777216);
  f16_t* Vth  = (f16_t*)alloc(16777216);
  f16_t* strK = (f16_t*)alloc(2097152);
  f16_t* strVt= (f16_t*)alloc(2097152);
  f16_t* conc = (f16_t*)alloc(18874368);
  float* stRm = (float*)alloc(524288);
  float* stRr = (float*)alloc(32768);
  float* mbias= (float*)alloc(32768);
  float* rbias= (float*)alloc(32768);

  // prep: converts + mask biases + weight transposes, one launch
  prep_all<<<17312,256,0,stream>>>(query, key, value, x_rsa, mask, rmask,
                                   q16, k16, v16, xrf, mbias, rbias,
                                   Wq, Wk, Wv, Wsk, Wsv, Wo,
                                   wqT, wkT, wvT, wskT, wsvT, woT);

  // all input projections in one launch: z=0 -> str (bx 0/1), z=1..3 -> Q/K/V
  {
    GPack pm{};
    pm.g[0] = {q16, wqT,  bq,  (void*)Qh,    1024u,1024u,0u,   1024u, 1};
    pm.g[1] = {k16, wkT,  bk,  (void*)Kh,    1024u,1024u,0u,   1024u, 1};
    pm.g[2] = {v16, wvT,  bv,  (void*)Vth,   1024u,1024u,1024u,1024u, 2};
    pm.g[3] = {k16, wskT, bsk, (void*)strK,  1024u,1024u,128u, 1024u, 3};
    pm.g[4] = {v16, wsvT, bsv, (void*)strVt, 1024u,1024u,128u, 1024u, 2};
    pm.single = -1;
    gemm_bt<<<dim3(8,64,4),256,0,stream>>>(pm);
  }

  float* outp  = (float*)d_out;
  float* attnp = outp + 8388608;
  float* rsap  = outp + 8388608 + 134217728;

  // attention stats (rsa y<8 first, then main)
  attn_pass1_all<<<dim3(8,136),512,0,stream>>>(Qh, Kh, mbias, stRm, xrf, strK, rbias, stRr);

  // attention pass2 (softmax out + PV into concat)
  attn_pass2_all<<<dim3(8,136),512,0,stream>>>(Qh, Kh, Vth, mbias, stRm, attnp,
                                               xrf, strK, strVt, rbias, stRr, rsap, conc);

  // output projection
  {
    GPack po{};
    po.g[0] = {conc, woT, bo, (void*)outp, 1152u,1152u,1024u,1152u, 0};
    po.g[1] = po.g[0]; po.g[2] = po.g[0]; po.g[3] = po.g[0]; po.g[4] = po.g[0];
    po.single = 0;
    gemm_bt<<<dim3(8,64,1),256,0,stream>>>(po);
  }

  (void)in_sizes; (void)n_in; (void)out_size; (void)ws_size;
}